// Round 1
// 114.469 us; speedup vs baseline: 1.0152x; 1.0152x over previous
//
#include <hip/hip_runtime.h>

#define HH   128
#define WW   128
#define HW   (HH * WW)
#define CC   64
#define TILE 16
#define HALO 20
#define NHP  (HALO * HALO)   // 400 halo pixels = 25 exact 16-px MFMA tiles
#define SWZ(r) (((r) >> 1) & 7)

typedef unsigned int uint32;
typedef _Float16 h2   __attribute__((ext_vector_type(2)));
typedef __fp16   h2b  __attribute__((ext_vector_type(2)));
typedef _Float16 h8   __attribute__((ext_vector_type(8)));
typedef float    f32x4 __attribute__((ext_vector_type(4)));

__device__ __forceinline__ uint32 pkrtz(float a, float b) {
    h2b r = __builtin_amdgcn_cvt_pkrtz(a, b);
    return __builtin_bit_cast(uint32, r);
}
__device__ __forceinline__ float dot2(uint32 a, uint32 b, float c) {
#if __has_builtin(__builtin_amdgcn_fdot2)
    return __builtin_amdgcn_fdot2(__builtin_bit_cast(h2b, a),
                                  __builtin_bit_cast(h2b, b), c, false);
#else
    h2 x = __builtin_bit_cast(h2, a), y = __builtin_bit_cast(h2, b);
    return c + (float)x.x * (float)y.x + (float)x.y * (float)y.y;
#endif
}
__device__ __forceinline__ f32x4 mfma16(uint4 a, uint4 b, f32x4 c) {
    return __builtin_amdgcn_mfma_f32_16x16x32_f16(
        __builtin_bit_cast(h8, a), __builtin_bit_cast(h8, b), c, 0, 0, 0);
}
__device__ __forceinline__ uint4 pack_w8(const float* __restrict__ w) {
    const float4 lo = *(const float4*)w;
    const float4 hi = *(const float4*)(w + 4);
    uint4 r;
    r.x = pkrtz(lo.x, lo.y); r.y = pkrtz(lo.z, lo.w);
    r.z = pkrtz(hi.x, hi.y); r.w = pkrtz(hi.z, hi.w);
    return r;
}

// ---------------------------------------------------------------------------
// Fused local attention, 16x16 tiles, 1 block/CU, 16 waves.
// A: y-halo -> q-halo -> agg(rows 0..255).  B: x-halo -> v-halo.
// Residual x saved to regs (f16) before v overwrites B. 5 barriers.
// Halo overfetch 1.56x (was 2.25x); 16-wide rows => full-line stores.
// LDS chunk swizzle (row>>1)&7 keeps b128 accesses bank-balanced for both
// the pair-staging writes (even/odd rows) and all tile reads.
// ---------------------------------------------------------------------------
__global__ __launch_bounds__(1024, 4)
void fused_attn(const float* __restrict__ x, const float* __restrict__ y,
                const float* __restrict__ wx, const float* __restrict__ bx,
                const float* __restrict__ wy, const float* __restrict__ by,
                const float* __restrict__ wo, const float* __restrict__ bo,
                float* __restrict__ out)
{
    __shared__ uint32 Ah[NHP * 32];   // 50 KiB
    __shared__ uint32 Bh[NHP * 32];   // 50 KiB

    // ---- XCD-aware tile mapping: lin%8 = XCD; each XCD owns a contiguous
    // 4-tile-row x 8-tile-col half-batch region (halo overlap stays in-L2) ----
    const int lin  = blockIdx.x;          // 0..255
    const int xcd  = lin & 7;
    const int rr   = lin >> 3;            // 0..31 within XCD
    const int b    = xcd >> 1;            // 2 XCDs per batch
    const int half = xcd & 1;             // top/bottom 4 tile-rows
    const int ty0  = ((rr >> 3) + half * 4) * TILE;
    const int tx0  = (rr & 7) * TILE;

    const int t = threadIdx.x;

    // ---- stage y->A, x->B as f16, pixel-PAIR float2 loads, swizzled ----
    for (int i = t; i < NHP * 8 / 2; i += 1024) {      // 1600 pair-items
        const int c   = i / 200;                       // channel octet 0..7
        const int rem = i - c * 200;
        const int hy  = rem / 10;
        const int hx  = (rem - hy * 10) * 2;           // even column
        const int pix = hy * HALO + hx;
        int gy = ty0 + hy - 2, gx = tx0 + hx - 2;      // gx even
        const bool ok = ((unsigned)gy < HH) & ((unsigned)gx < (WW - 1));
        if (!ok) { gy = 0; gx = 0; }     // clamp; conv out zeroed at write
        const size_t base = (size_t)b * CC * HW + (size_t)(c * 8) * HW
                          + (size_t)gy * WW + gx;
        float2 yv[8], xv[8];
        #pragma unroll
        for (int j = 0; j < 8; ++j) {
            yv[j] = *(const float2*)(y + base + (size_t)j * HW);
            xv[j] = *(const float2*)(x + base + (size_t)j * HW);
        }
        uint4 q0, q1;
        q0.x = pkrtz(yv[0].x, yv[1].x); q0.y = pkrtz(yv[2].x, yv[3].x);
        q0.z = pkrtz(yv[4].x, yv[5].x); q0.w = pkrtz(yv[6].x, yv[7].x);
        q1.x = pkrtz(yv[0].y, yv[1].y); q1.y = pkrtz(yv[2].y, yv[3].y);
        q1.z = pkrtz(yv[4].y, yv[5].y); q1.w = pkrtz(yv[6].y, yv[7].y);
        *(uint4*)&Ah[pix * 32 + (c ^ SWZ(pix)) * 4]           = q0;
        *(uint4*)&Ah[(pix + 1) * 32 + (c ^ SWZ(pix + 1)) * 4] = q1;
        q0.x = pkrtz(xv[0].x, xv[1].x); q0.y = pkrtz(xv[2].x, xv[3].x);
        q0.z = pkrtz(xv[4].x, xv[5].x); q0.w = pkrtz(xv[6].x, xv[7].x);
        q1.x = pkrtz(xv[0].y, xv[1].y); q1.y = pkrtz(xv[2].y, xv[3].y);
        q1.z = pkrtz(xv[4].y, xv[5].y); q1.w = pkrtz(xv[6].y, xv[7].y);
        *(uint4*)&Bh[pix * 32 + (c ^ SWZ(pix)) * 4]           = q0;
        *(uint4*)&Bh[(pix + 1) * 32 + (c ^ SWZ(pix + 1)) * 4] = q1;
    }
    __syncthreads();                                   // [1]

    const int wv = t >> 6;        // wave id 0..15
    const int ln = t & 63;
    const int lm = ln & 15;
    const int qd = ln >> 4;
    const int ot = wv & 3;        // this wave's 16-oc tile

    // ---- q-conv + v-conv (interleaved MFMA) + residual slice save ----
    // jobs j = wv + 16k over 100 = 25 pixel-tiles x 4 oc-tiles
    f32x4 accq[7], accv[7];
    uint2 xres[4];
    {
        const uint4 aq0 = pack_w8(wy + (ot * 16 + lm) * CC + qd * 8);
        const uint4 aq1 = pack_w8(wy + (ot * 16 + lm) * CC + qd * 8 + 32);
        const uint4 av0 = pack_w8(wx + (ot * 16 + lm) * CC + qd * 8);
        const uint4 av1 = pack_w8(wx + (ot * 16 + lm) * CC + qd * 8 + 32);
        #pragma unroll
        for (int k = 0; k < 7; ++k) {
            const int j = wv + k * 16;
            if (j < 100) {
                const int px = (j >> 2) * 16 + lm, sw = SWZ(px);
                const uint4 b0 = *(const uint4*)&Ah[px * 32 + ((qd    ) ^ sw) * 4];
                const uint4 b1 = *(const uint4*)&Ah[px * 32 + ((qd + 4) ^ sw) * 4];
                f32x4 a = {0.f, 0.f, 0.f, 0.f};
                a = mfma16(aq0, b0, a); a = mfma16(aq1, b1, a); accq[k] = a;
                const uint4 c0 = *(const uint4*)&Bh[px * 32 + ((qd    ) ^ sw) * 4];
                const uint4 c1 = *(const uint4*)&Bh[px * 32 + ((qd + 4) ^ sw) * 4];
                f32x4 v = {0.f, 0.f, 0.f, 0.f};
                v = mfma16(av0, c0, v); v = mfma16(av1, c1, v); accv[k] = v;
            }
        }
        #pragma unroll
        for (int k = 0; k < 4; ++k) {   // f16 x at this lane's final out px/chs
            const int px = ((wv >> 2) + k * 4) * 16 + lm;        // 0..255
            const int hpix = ((px >> 4) + 2) * HALO + (px & 15) + 2;
            const int chunk = ot * 2 + (qd >> 1);
            xres[k] = *(const uint2*)
                &Bh[hpix * 32 + (chunk ^ SWZ(hpix)) * 4 + (qd & 1) * 2];
        }
    }
    __syncthreads();                                   // [2] halo reads done

    // ---- write q->A, v->B (OOB => 0: unfold zero-pad is AFTER conv+bias) ----
    {
        const float4 bq = *(const float4*)(by + ot * 16 + qd * 4);
        const float4 bv = *(const float4*)(bx + ot * 16 + qd * 4);
        const int chunk = ot * 2 + (qd >> 1);
        #pragma unroll
        for (int k = 0; k < 7; ++k) {
            const int j = wv + k * 16;
            if (j < 100) {
                const int px = (j >> 2) * 16 + lm;
                const int hy = px / HALO, hx = px - hy * HALO;
                const int gy = ty0 + hy - 2, gx = tx0 + hx - 2;
                uint2 wq = {0u, 0u}, wvv = {0u, 0u};
                if (((unsigned)gy < HH) & ((unsigned)gx < WW)) {
                    wq.x  = pkrtz(accq[k].x + bq.x, accq[k].y + bq.y);
                    wq.y  = pkrtz(accq[k].z + bq.z, accq[k].w + bq.w);
                    wvv.x = pkrtz(accv[k].x + bv.x, accv[k].y + bv.y);
                    wvv.y = pkrtz(accv[k].z + bv.z, accv[k].w + bv.w);
                }
                const int off = px * 32 + (chunk ^ SWZ(px)) * 4 + (qd & 1) * 2;
                *(uint2*)&Ah[off] = wq;
                *(uint2*)&Bh[off] = wvv;
            }
        }
    }
    __syncthreads();                                   // [3] q,v visible

    // ---- scores (from A): 1 pixel per thread-quad, 16 ch per sub-lane ----
    const int p    = t >> 2, sub = t & 3;              // p 0..255
    const int py   = p >> 4, pxl = p & 15;
    const int crow = (py + 2) * HALO + (pxl + 2);

    uint32 qc[8];
    {
        const int c0 = ((2 * sub)     ^ SWZ(crow)) * 4;
        const int c1 = ((2 * sub + 1) ^ SWZ(crow)) * 4;
        *(uint4*)&qc[0] = *(const uint4*)&Ah[crow * 32 + c0];
        *(uint4*)&qc[4] = *(const uint4*)&Ah[crow * 32 + c1];
    }

    float sc[25];
    #pragma unroll
    for (int dy = 0; dy < 5; ++dy)
        #pragma unroll
        for (int dx = 0; dx < 5; ++dx) {
            const int nrow = (py + dy) * HALO + (pxl + dx);
            const int c0 = ((2 * sub)     ^ SWZ(nrow)) * 4;
            const int c1 = ((2 * sub + 1) ^ SWZ(nrow)) * 4;
            const uint4 r0 = *(const uint4*)&Ah[nrow * 32 + c0];
            const uint4 r1 = *(const uint4*)&Ah[nrow * 32 + c1];
            float s = 0.f;
            s = dot2(qc[0], r0.x, s); s = dot2(qc[1], r0.y, s);
            s = dot2(qc[2], r0.z, s); s = dot2(qc[3], r0.w, s);
            s = dot2(qc[4], r1.x, s); s = dot2(qc[5], r1.y, s);
            s = dot2(qc[6], r1.z, s); s = dot2(qc[7], r1.w, s);
            s += __shfl_xor(s, 1);
            s += __shfl_xor(s, 2);      // identical across the 4 sub-lanes
            sc[dy * 5 + dx] = s;
        }

    // ---- softmax over 25 ----
    float mx = sc[0];
    #pragma unroll
    for (int k = 1; k < 25; ++k) mx = fmaxf(mx, sc[k]);
    float sum = 0.f;
    #pragma unroll
    for (int k = 0; k < 25; ++k) { sc[k] = __expf(sc[k] - mx); sum += sc[k]; }
    const float inv = 1.f / sum;

    // ---- aggregate v (from B, packed f16 fma) ----
    h2 ag[8];
    #pragma unroll
    for (int k = 0; k < 8; ++k) ag[k] = (h2)(_Float16)0;
    #pragma unroll
    for (int dy = 0; dy < 5; ++dy)
        #pragma unroll
        for (int dx = 0; dx < 5; ++dx) {
            const int nrow = (py + dy) * HALO + (pxl + dx);
            const int c0 = ((2 * sub)     ^ SWZ(nrow)) * 4;
            const int c1 = ((2 * sub + 1) ^ SWZ(nrow)) * 4;
            const uint4 r0 = *(const uint4*)&Bh[nrow * 32 + c0];
            const uint4 r1 = *(const uint4*)&Bh[nrow * 32 + c1];
            const _Float16 af = (_Float16)(sc[dy * 5 + dx] * inv);
            const h2 a2 = {af, af};
            ag[0] += a2 * __builtin_bit_cast(h2, r0.x);
            ag[1] += a2 * __builtin_bit_cast(h2, r0.y);
            ag[2] += a2 * __builtin_bit_cast(h2, r0.z);
            ag[3] += a2 * __builtin_bit_cast(h2, r0.w);
            ag[4] += a2 * __builtin_bit_cast(h2, r1.x);
            ag[5] += a2 * __builtin_bit_cast(h2, r1.y);
            ag[6] += a2 * __builtin_bit_cast(h2, r1.z);
            ag[7] += a2 * __builtin_bit_cast(h2, r1.w);
        }

    __syncthreads();                                   // [4] A,B reads done
    {                 // agg -> A rows 0..255 (same swizzled layout)
        const int c0 = ((2 * sub)     ^ SWZ(p)) * 4;
        const int c1 = ((2 * sub + 1) ^ SWZ(p)) * 4;
        uint4 w0, w1;
        w0.x = __builtin_bit_cast(uint32, ag[0]); w0.y = __builtin_bit_cast(uint32, ag[1]);
        w0.z = __builtin_bit_cast(uint32, ag[2]); w0.w = __builtin_bit_cast(uint32, ag[3]);
        w1.x = __builtin_bit_cast(uint32, ag[4]); w1.y = __builtin_bit_cast(uint32, ag[5]);
        w1.z = __builtin_bit_cast(uint32, ag[6]); w1.w = __builtin_bit_cast(uint32, ag[7]);
        *(uint4*)&Ah[p * 32 + c0] = w0;
        *(uint4*)&Ah[p * 32 + c1] = w1;
    }
    __syncthreads();                                   // [5]

    // ---- final conv (MFMA) + bias + f16 residual from regs ----
    {
        const uint4 a0 = pack_w8(wo + (ot * 16 + lm) * CC + qd * 8);
        const uint4 a1 = pack_w8(wo + (ot * 16 + lm) * CC + qd * 8 + 32);
        const float4 bq = *(const float4*)(bo + ot * 16 + qd * 4);
        #pragma unroll
        for (int k = 0; k < 4; ++k) {
            const int px = ((wv >> 2) + k * 4) * 16 + lm, sw = SWZ(px);
            const uint4 b0 = *(const uint4*)&Ah[px * 32 + ((qd    ) ^ sw) * 4];
            const uint4 b1 = *(const uint4*)&Ah[px * 32 + ((qd + 4) ^ sw) * 4];
            f32x4 a = {0.f, 0.f, 0.f, 0.f};
            a = mfma16(a0, b0, a);
            a = mfma16(a1, b1, a);
            const int gh = ty0 + (px >> 4), gw = tx0 + (px & 15);
            const h2 xp0 = __builtin_bit_cast(h2, xres[k].x);  // ch qd*4+0,1
            const h2 xp1 = __builtin_bit_cast(h2, xres[k].y);  // ch qd*4+2,3
            const float rv[4] = {(float)xp0.x, (float)xp0.y,
                                 (float)xp1.x, (float)xp1.y};
            const float av4[4] = {a.x + bq.x, a.y + bq.y, a.z + bq.z, a.w + bq.w};
            #pragma unroll
            for (int r = 0; r < 4; ++r) {
                const int oc = ot * 16 + qd * 4 + r;
                const size_t ad = (size_t)(b * CC + oc) * HW + (size_t)gh * WW + gw;
                out[ad] = av4[r] + rv[r];   // 16 lanes -> one full 64B line
            }
        }
    }
}

// ---------------------------------------------------------------------------
extern "C" void kernel_launch(void* const* d_in, const int* in_sizes, int n_in,
                              void* d_out, int out_size, void* d_ws, size_t ws_size,
                              hipStream_t stream) {
    const float* x  = (const float*)d_in[0];
    const float* y  = (const float*)d_in[1];
    const float* wx = (const float*)d_in[2];
    const float* bx = (const float*)d_in[3];
    const float* wy = (const float*)d_in[4];
    const float* by = (const float*)d_in[5];
    const float* wo = (const float*)d_in[6];
    const float* bo = (const float*)d_in[7];
    float* out = (float*)d_out;
    (void)d_ws; (void)ws_size;

    fused_attn<<<dim3(256), 1024, 0, stream>>>(x, y, wx, bx, wy, by, wo, bo, out);
}